// Round 10
// baseline (44.932 us; speedup 1.0000x reference)
//
#include <hip/hip_runtime.h>
#include <hip/hip_fp8.h>

typedef __attribute__((ext_vector_type(8))) short short8;
typedef __attribute__((ext_vector_type(4))) float f32x4;

// round-to-nearest-even f32 -> bf16
__device__ __forceinline__ unsigned short f2bf(float f) {
    unsigned u = __float_as_uint(f);
    u += 0x7FFFu + ((u >> 16) & 1u);
    return (unsigned short)(u >> 16);
}

__device__ __forceinline__ unsigned char f2fp8(float f) {
    __hip_fp8_e4m3 q(f);            // OCP e4m3fn, HW cvt on gfx950
    return q.__x;
}

// ---------------------------------------------------------------------------
// Prepass: convert x [Mpad*K] and w [N*K] f32 -> fp8 e4m3 in workspace.
// ---------------------------------------------------------------------------
__global__ void eventprop_cvt8_kernel(const float* __restrict__ x, const float* __restrict__ w,
                                      unsigned char* __restrict__ x8, unsigned char* __restrict__ w8,
                                      const int nx, const int ntot)
{
    const int i = blockIdx.x * blockDim.x + threadIdx.x;
    const int e0 = i * 8;
    if (e0 >= ntot) return;
    const float* src;
    unsigned char* dst;
    if (e0 < nx) { src = x + e0; dst = x8 + e0; }
    else         { src = w + (e0 - nx); dst = w8 + (e0 - nx); }
    const float4 f0 = *(const float4*)(src);
    const float4 f1 = *(const float4*)(src + 4);
    uchar4 a, b;
    a.x = f2fp8(f0.x); a.y = f2fp8(f0.y); a.z = f2fp8(f0.z); a.w = f2fp8(f0.w);
    b.x = f2fp8(f1.x); b.y = f2fp8(f1.y); b.z = f2fp8(f1.z); b.w = f2fp8(f1.w);
    uint2 v;
    v.x = *(unsigned int*)&a;
    v.y = *(unsigned int*)&b;
    *(uint2*)dst = v;               // 8B aligned (e0 % 8 == 0)
}

// ---------------------------------------------------------------------------
// fp8 GEMM, round-8 single-buffer template re-tiled for full occupancy:
// 128x64 block-tile, BK=128, 512 threads = 8 waves (4m x 2n), wave-tile 32x32.
// LDS 24KB -> 4 blocks/CU (thread-limited) = 32 waves/CU = 100% occupancy.
// Both-sides 16B XOR swizzle (rule #21) identical to round 8; XCD chunked
// blockIdx swizzle; __syncthreads per K-step (compiler drains vmcnt).
// Output: bf16 cur into workspace.
// ---------------------------------------------------------------------------
__global__ __launch_bounds__(512, 8) void eventprop_gemm_fp8_kernel(
    const unsigned char* __restrict__ X8, const unsigned char* __restrict__ W8,
    unsigned short* __restrict__ Cb, const int K, const int N, const int nbn)
{
    __shared__ unsigned char As[128 * 128];   // 16 KB
    __shared__ unsigned char Bs[64 * 128];    // 8 KB

    // bijective XCD chunked swizzle (gridDim.x % 8 == 0)
    const int bid0 = blockIdx.x;
    const int cpx = gridDim.x >> 3;                    // 128
    const int bid = (bid0 & 7) * cpx + (bid0 >> 3);
    const int bm = bid / nbn, bn = bid % nbn;          // nbn = 16
    const int m0 = bm * 128, n0 = bn * 64;

    const int tid = threadIdx.x;
    const int lane = tid & 63;
    const int wave = tid >> 6;                   // 0..7
    const int wr = wave >> 1, wc = wave & 1;     // 4x2 waves: 32(m) x 32(n) each
    const int lrow = lane & 15, kg = lane >> 4;  // MFMA fragment row / k-group
    const int srow = lane >> 3;                  // staging: row within 8-row group
    const int scol = (((lane & 7) ^ srow) * 16); // staging: SWIZZLED global byte col

    f32x4 acc[2][2] = {};

    for (int kt = 0; kt < K; kt += 128) {
        // ---- stage A (16 x 1KB issues, 2/wave) + B (8 issues, 1/wave) ----
        #pragma unroll
        for (int jj = 0; jj < 2; ++jj) {
            const int j = wave * 2 + jj;              // wave-uniform 0..15
            const int row = j * 8 + srow;
            const unsigned char* ga = &X8[(size_t)(m0 + row) * K + kt + scol];
            __builtin_amdgcn_global_load_lds(
                (const __attribute__((address_space(1))) unsigned int*)ga,
                (__attribute__((address_space(3))) unsigned int*)&As[j * 1024], 16, 0, 0);
        }
        {
            const int j = wave;                       // wave-uniform 0..7
            const int row = j * 8 + srow;
            const unsigned char* gb = &W8[(size_t)(n0 + row) * K + kt + scol];
            __builtin_amdgcn_global_load_lds(
                (const __attribute__((address_space(1))) unsigned int*)gb,
                (__attribute__((address_space(3))) unsigned int*)&Bs[j * 1024], 16, 0, 0);
        }
        __syncthreads();   // drains vmcnt(0): tile ready

        // ---- fragments + MFMA: 4 k-slices of 32, swizzled ds_read cols ----
        const int rx = (lrow & 7) << 4;              // read-side XOR term
        long a[4][2], b[4][2];
        #pragma unroll
        for (int ks = 0; ks < 4; ++ks) {
            const int cc = (ks * 32 + kg * 8) ^ rx;  // 8B-aligned swizzled col
            #pragma unroll
            for (int mi = 0; mi < 2; ++mi)
                a[ks][mi] = *(const long*)&As[(wr * 32 + mi * 16 + lrow) * 128 + cc];
            #pragma unroll
            for (int ni = 0; ni < 2; ++ni)
                b[ks][ni] = *(const long*)&Bs[(wc * 32 + ni * 16 + lrow) * 128 + cc];
        }
        #pragma unroll
        for (int ks = 0; ks < 4; ++ks)
            #pragma unroll
            for (int mi = 0; mi < 2; ++mi)
                #pragma unroll
                for (int ni = 0; ni < 2; ++ni)
                    acc[mi][ni] = __builtin_amdgcn_mfma_f32_16x16x32_fp8_fp8(
                        a[ks][mi], b[ks][ni], acc[mi][ni], 0, 0, 0);
        __syncthreads();
    }

    // ---- epilogue: C/D layout col=lane&15, row=(lane>>4)*4+reg [m89]; bf16 out ----
    const int r0 = kg * 4;
    #pragma unroll
    for (int mi = 0; mi < 2; ++mi) {
        #pragma unroll
        for (int ni = 0; ni < 2; ++ni) {
            #pragma unroll
            for (int r = 0; r < 4; ++r) {
                const int row = m0 + wr * 32 + mi * 16 + r0 + r;
                const int col = n0 + wc * 32 + ni * 16 + lrow;
                Cb[(size_t)row * N + col] = f2bf(acc[mi][ni][r]);
            }
        }
    }
}

// ---------------------------------------------------------------------------
// Scan (ws path): cur bf16 [T][BO] in workspace -> spikes f32 [T][BO] in out.
// ---------------------------------------------------------------------------
__global__ void eventprop_scan_bf16_kernel(const unsigned short* __restrict__ cur,
                                           float* __restrict__ out, const int BO)
{
    const int j = blockIdx.x * blockDim.x + threadIdx.x;  // 0..BO/2-1
    const int col = j * 2;
    float V0 = 0.f, I0 = 0.f, V1 = 0.f, I1 = 0.f;
    unsigned int c[8];
    #pragma unroll
    for (int p = 0; p < 8; ++p)
        c[p] = *(const unsigned int*)&cur[(size_t)p * BO + col];   // cur[0..7]
    *(float2*)&out[col] = make_float2(0.f, 0.f);                   // out[0] = 0

    #pragma unroll 1
    for (int i = 0; i < 120; i += 8) {
        #pragma unroll
        for (int p = 0; p < 8; ++p) {
            const int it = i + p;                                  // 0..119
            const unsigned int cn = *(const unsigned int*)&cur[(size_t)(it + 8) * BO + col];
            const float Vn0 = 0.9f * V0 + 0.1f * I0;
            const float Vn1 = 0.9f * V1 + 0.1f * I1;
            const float s0 = (Vn0 > 1.0f) ? 1.0f : 0.0f;
            const float s1 = (Vn1 > 1.0f) ? 1.0f : 0.0f;
            I0 = __uint_as_float(c[p] << 16);                      // lo bf16
            I1 = __uint_as_float(c[p] & 0xFFFF0000u);              // hi bf16
            V0 = (1.0f - s0) * Vn0;
            V1 = (1.0f - s1) * Vn1;
            *(float2*)&out[(size_t)(it + 1) * BO + col] = make_float2(s0, s1);
            c[p] = cn;
        }
    }
    // tail: it = 120..126 (c[7] = slot-127 garbage, never consumed)
    #pragma unroll
    for (int p = 0; p < 7; ++p) {
        const int it = 120 + p;
        const float Vn0 = 0.9f * V0 + 0.1f * I0;
        const float Vn1 = 0.9f * V1 + 0.1f * I1;
        const float s0 = (Vn0 > 1.0f) ? 1.0f : 0.0f;
        const float s1 = (Vn1 > 1.0f) ? 1.0f : 0.0f;
        I0 = __uint_as_float(c[p] << 16);
        I1 = __uint_as_float(c[p] & 0xFFFF0000u);
        V0 = (1.0f - s0) * Vn0;
        V1 = (1.0f - s1) * Vn1;
        *(float2*)&out[(size_t)(it + 1) * BO + col] = make_float2(s0, s1);
    }
}

// ---------------------------------------------------------------------------
// Fallback GEMM (inline f32->bf16, 128x128, BK=32, f32 cur to out) if ws small.
// ---------------------------------------------------------------------------
__global__ __launch_bounds__(256, 2) void eventprop_gemm_f32in_kernel(
    const float* __restrict__ X, const float* __restrict__ W, float* __restrict__ C,
    const int K, const int N, const int nbn)
{
    __shared__ unsigned short As[128][32];
    __shared__ unsigned short Bs[128][32];
    const int bid = blockIdx.x;
    const int bm = bid / nbn, bn = bid % nbn;
    const int m0 = bm * 128, n0 = bn * 128;
    const int tid = threadIdx.x;
    const int lane = tid & 63;
    const int wave = tid >> 6;
    const int wr = wave >> 1, wc = wave & 1;
    const int lrow = lane & 15, kg = lane >> 4;

    f32x4 acc[4][4] = {};
    for (int kt = 0; kt < K; kt += 32) {
        #pragma unroll
        for (int p = 0; p < 4; ++p) {
            const int idx = p * 256 + tid;
            const int row = idx >> 3;
            const int c4  = (idx & 7) * 4;
            const float4 fa = *(const float4*)&X[(size_t)(m0 + row) * K + kt + c4];
            ushort4 ua; ua.x = f2bf(fa.x); ua.y = f2bf(fa.y); ua.z = f2bf(fa.z); ua.w = f2bf(fa.w);
            *(ushort4*)&As[row][c4] = ua;
            const float4 fb = *(const float4*)&W[(size_t)(n0 + row) * K + kt + c4];
            ushort4 ub; ub.x = f2bf(fb.x); ub.y = f2bf(fb.y); ub.z = f2bf(fb.z); ub.w = f2bf(fb.w);
            *(ushort4*)&Bs[row][c4] = ub;
        }
        __syncthreads();
        short8 a[4], b[4];
        #pragma unroll
        for (int mi = 0; mi < 4; ++mi) a[mi] = *(const short8*)&As[wr * 64 + mi * 16 + lrow][kg * 8];
        #pragma unroll
        for (int ni = 0; ni < 4; ++ni) b[ni] = *(const short8*)&Bs[wc * 64 + ni * 16 + lrow][kg * 8];
        #pragma unroll
        for (int mi = 0; mi < 4; ++mi)
            #pragma unroll
            for (int ni = 0; ni < 4; ++ni)
                acc[mi][ni] = __builtin_amdgcn_mfma_f32_16x16x32_bf16(a[mi], b[ni], acc[mi][ni], 0, 0, 0);
        __syncthreads();
    }
    const int r0 = kg * 4;
    #pragma unroll
    for (int mi = 0; mi < 4; ++mi)
        #pragma unroll
        for (int ni = 0; ni < 4; ++ni)
            #pragma unroll
            for (int r = 0; r < 4; ++r)
                C[(size_t)(m0 + wr * 64 + mi * 16 + r0 + r) * N + (n0 + wc * 64 + ni * 16 + lrow)] = acc[mi][ni][r];
}

// ---------------------------------------------------------------------------
// Fallback scan: in-place on d_out (f32 cur), 8-deep prefetch ring.
// ---------------------------------------------------------------------------
__global__ void eventprop_scan_kernel(float* __restrict__ out, const int BO)
{
    const int idx = blockIdx.x * blockDim.x + threadIdx.x;
    float V = 0.f, I = 0.f;
    float c[8];
    #pragma unroll
    for (int p = 0; p < 8; ++p)
        c[p] = out[(size_t)p * BO + idx];
    out[idx] = 0.f;
    #pragma unroll 1
    for (int i = 0; i < 120; i += 8) {
        #pragma unroll
        for (int p = 0; p < 8; ++p) {
            const int it = i + p;
            const float cn = out[(size_t)(it + 8) * BO + idx];
            const float Vn = 0.9f * V + 0.1f * I;
            const float s = (Vn > 1.0f) ? 1.0f : 0.0f;
            I = c[p];
            V = (1.0f - s) * Vn;
            out[(size_t)(it + 1) * BO + idx] = s;
            c[p] = cn;
        }
    }
    #pragma unroll
    for (int p = 0; p < 7; ++p) {
        const int it = 120 + p;
        const float Vn = 0.9f * V + 0.1f * I;
        const float s = (Vn > 1.0f) ? 1.0f : 0.0f;
        I = c[p];
        V = (1.0f - s) * Vn;
        out[(size_t)(it + 1) * BO + idx] = s;
    }
}

extern "C" void kernel_launch(void* const* d_in, const int* in_sizes, int n_in,
                              void* d_out, int out_size, void* d_ws, size_t ws_size,
                              hipStream_t stream) {
    const float* x = (const float*)d_in[0];   // [T, B, IN] f32
    const float* w = (const float*)d_in[1];   // [OUT, IN] f32
    float* out = (float*)d_out;               // [T, B, OUT] f32

    const int T = 128, B = 64, IN = 1024, OUT = 1024;
    const int Mpad = T * B;                   // 8192
    const int BO = B * OUT;                   // 65536
    const size_t nx = (size_t)Mpad * IN;      // 8388608
    const size_t nw = (size_t)OUT * IN;       // 1048576
    const size_t ncur = (size_t)Mpad * OUT;   // 8388608
    const size_t need = ncur * 2 + nx + nw;   // 26.2 MB

    if (ws_size >= need) {
        unsigned short* curb = (unsigned short*)d_ws;
        unsigned char* x8 = (unsigned char*)(curb + ncur);
        unsigned char* w8 = x8 + nx;
        const int ntot = (int)(nx + nw);
        const int cvt_blocks = (ntot / 8 + 255) / 256;  // 4608
        eventprop_cvt8_kernel<<<dim3(cvt_blocks), dim3(256), 0, stream>>>(x, w, x8, w8, (int)nx, ntot);
        const int nbn = OUT / 64;                        // 16
        const int nblocks = (Mpad / 128) * nbn;          // 1024
        eventprop_gemm_fp8_kernel<<<dim3(nblocks), dim3(512), 0, stream>>>(x8, w8, curb, IN, OUT, nbn);
        eventprop_scan_bf16_kernel<<<dim3((BO / 2) / 256), dim3(256), 0, stream>>>(curb, out, BO);
    } else {
        const int nbn = OUT / 128;
        const int nblocks = (Mpad / 128) * nbn;          // 512
        eventprop_gemm_f32in_kernel<<<dim3(nblocks), dim3(256), 0, stream>>>(x, w, out, IN, OUT, nbn);
        eventprop_scan_kernel<<<dim3(BO / 256), dim3(256), 0, stream>>>(out, BO);
    }
}

// Round 11
// 34.524 us; speedup vs baseline: 1.3015x; 1.3015x over previous
//
#include <hip/hip_runtime.h>
#include <hip/hip_fp8.h>

typedef __attribute__((ext_vector_type(8))) short short8;
typedef __attribute__((ext_vector_type(4))) float f32x4;

// round-to-nearest-even f32 -> bf16
__device__ __forceinline__ unsigned short f2bf(float f) {
    unsigned u = __float_as_uint(f);
    u += 0x7FFFu + ((u >> 16) & 1u);
    return (unsigned short)(u >> 16);
}

__device__ __forceinline__ unsigned char f2fp8(float f) {
    __hip_fp8_e4m3 q(f);            // OCP e4m3fn, HW cvt on gfx950
    return q.__x;
}

// ---------------------------------------------------------------------------
// Prepass: convert x [Mpad*K] and w [N*K] f32 -> fp8 e4m3 in workspace.
// ---------------------------------------------------------------------------
__global__ void eventprop_cvt8_kernel(const float* __restrict__ x, const float* __restrict__ w,
                                      unsigned char* __restrict__ x8, unsigned char* __restrict__ w8,
                                      const int nx, const int ntot)
{
    const int i = blockIdx.x * blockDim.x + threadIdx.x;
    const int e0 = i * 8;
    if (e0 >= ntot) return;
    const float* src;
    unsigned char* dst;
    if (e0 < nx) { src = x + e0; dst = x8 + e0; }
    else         { src = w + (e0 - nx); dst = w8 + (e0 - nx); }
    const float4 f0 = *(const float4*)(src);
    const float4 f1 = *(const float4*)(src + 4);
    uchar4 a, b;
    a.x = f2fp8(f0.x); a.y = f2fp8(f0.y); a.z = f2fp8(f0.z); a.w = f2fp8(f0.w);
    b.x = f2fp8(f1.x); b.y = f2fp8(f1.y); b.z = f2fp8(f1.z); b.w = f2fp8(f1.w);
    uint2 v;
    v.x = *(unsigned int*)&a;
    v.y = *(unsigned int*)&b;
    *(uint2*)dst = v;               // 8B aligned (e0 % 8 == 0)
}

// ---------------------------------------------------------------------------
// Fused fp8 GEMM + scan. Round-8 K-loop verbatim (128x64 tile, BK=128,
// 4 waves 64x32, both-sides 16B XOR swizzle, single-buffer, __syncthreads).
// Grid re-tiled along TIME: block (bm=b, bn=o-tile) computes A-rows
// {t*64 + b, t=0..127} = all T timesteps of batch b x 64 out-columns.
// Epilogue: acc -> LDS cur[128][65] f32 (aliases As/Bs; stride-65 pads
// bank conflicts away), barrier, wave 0 scans 64 independent columns
// (127 serial steps) writing spikes straight to d_out. Deletes the curb
// round-trip (33.5MB) and the scan kernel entirely; scan consumes f32 cur.
// LDS 33.3KB -> 4 blocks/CU with __launch_bounds__(256,4).
// ---------------------------------------------------------------------------
__global__ __launch_bounds__(256, 4) void eventprop_gemm_scan_fp8_kernel(
    const unsigned char* __restrict__ X8, const unsigned char* __restrict__ W8,
    float* __restrict__ out, const int K, const int N, const int nbn)
{
    __shared__ float smemf[128 * 65];                     // 33280 B
    unsigned char* As = (unsigned char*)smemf;            // [128*128] fp8 (16 KB)
    unsigned char* Bs = As + 16384;                       // [64*128]  fp8 (8 KB)
    float* curLds = smemf;                                // [128][65] f32 (after K-loop)

    // bijective XCD chunked swizzle (gridDim.x % 8 == 0); groups same-b blocks
    const int bid0 = blockIdx.x;
    const int cpx = gridDim.x >> 3;                       // 128
    const int bid = (bid0 & 7) * cpx + (bid0 >> 3);
    const int bm = bid / nbn, bn = bid % nbn;             // bm = batch b, nbn = 16
    const int n0 = bn * 64;

    const int tid = threadIdx.x;
    const int lane = tid & 63;
    const int wave = tid >> 6;
    const int wr = wave >> 1, wc = wave & 1;     // 2x2 waves: 64(t) x 32(n) each
    const int lrow = lane & 15, kg = lane >> 4;  // MFMA fragment row / k-group
    const int srow = lane >> 3;                  // staging: row within 8-row group
    const int scol = (((lane & 7) ^ srow) * 16); // staging: SWIZZLED global byte col

    f32x4 acc[4][2] = {};

    for (int kt = 0; kt < K; kt += 128) {
        // ---- stage A (16 x 1KB issues, 4/wave) + B (8 issues, 2/wave) ----
        #pragma unroll
        for (int jj = 0; jj < 4; ++jj) {
            const int j = wave * 4 + jj;              // wave-uniform 0..15
            const int trow = j * 8 + srow;            // tile row = timestep t
            // global row of x8 = t*64 + b  (time-major [T][B][IN])
            const unsigned char* ga = &X8[(size_t)(trow * 64 + bm) * K + kt + scol];
            __builtin_amdgcn_global_load_lds(
                (const __attribute__((address_space(1))) unsigned int*)ga,
                (__attribute__((address_space(3))) unsigned int*)&As[j * 1024], 16, 0, 0);
        }
        #pragma unroll
        for (int jj = 0; jj < 2; ++jj) {
            const int j = wave * 2 + jj;              // wave-uniform 0..7
            const int row = j * 8 + srow;
            const unsigned char* gb = &W8[(size_t)(n0 + row) * K + kt + scol];
            __builtin_amdgcn_global_load_lds(
                (const __attribute__((address_space(1))) unsigned int*)gb,
                (__attribute__((address_space(3))) unsigned int*)&Bs[j * 1024], 16, 0, 0);
        }
        __syncthreads();   // drains vmcnt(0): tile ready

        // ---- fragments + MFMA: 4 k-slices of 32, swizzled ds_read cols ----
        const int rx = (lrow & 7) << 4;              // read-side XOR term
        long a[4][4], b[4][2];
        #pragma unroll
        for (int ks = 0; ks < 4; ++ks) {
            const int cc = (ks * 32 + kg * 8) ^ rx;  // 8B-aligned swizzled col
            #pragma unroll
            for (int mi = 0; mi < 4; ++mi)
                a[ks][mi] = *(const long*)&As[(wr * 64 + mi * 16 + lrow) * 128 + cc];
            #pragma unroll
            for (int ni = 0; ni < 2; ++ni)
                b[ks][ni] = *(const long*)&Bs[(wc * 32 + ni * 16 + lrow) * 128 + cc];
        }
        #pragma unroll
        for (int ks = 0; ks < 4; ++ks)
            #pragma unroll
            for (int mi = 0; mi < 4; ++mi)
                #pragma unroll
                for (int ni = 0; ni < 2; ++ni)
                    acc[mi][ni] = __builtin_amdgcn_mfma_f32_16x16x32_fp8_fp8(
                        a[ks][mi], b[ks][ni], acc[mi][ni], 0, 0, 0);
        __syncthreads();   // all waves done reading; LDS reusable
    }

    // ---- epilogue 1: acc -> curLds[t][col], stride 65 (C/D layout m89) ----
    const int r0 = kg * 4;
    #pragma unroll
    for (int mi = 0; mi < 4; ++mi) {
        #pragma unroll
        for (int ni = 0; ni < 2; ++ni) {
            #pragma unroll
            for (int r = 0; r < 4; ++r) {
                const int t = wr * 64 + mi * 16 + r0 + r;
                const int col = wc * 32 + ni * 16 + lrow;
                curLds[t * 65 + col] = acc[mi][ni][r];
            }
        }
    }
    __syncthreads();

    // ---- epilogue 2: per-column scan (wave 0; 64 independent columns) ----
    if (tid < 64) {
        const int col = tid;
        const size_t obase = (size_t)bm * N + n0 + col;   // out[.][bm][n0+col]
        const int BO = 64 * N;                            // 65536
        float V = 0.f, I = 0.f;
        float c[8];
        #pragma unroll
        for (int p = 0; p < 8; ++p)
            c[p] = curLds[p * 65 + col];                  // cur[0..7]
        out[obase] = 0.f;                                 // out[0] = 0
        #pragma unroll 1
        for (int i = 0; i < 120; i += 8) {
            #pragma unroll
            for (int p = 0; p < 8; ++p) {
                const int it = i + p;                     // 0..119
                const float cn = curLds[(it + 8) * 65 + col];  // <=127 (127 = garbage, unused)
                const float Vn = 0.9f * V + 0.1f * I;
                const float s = (Vn > 1.0f) ? 1.0f : 0.0f;
                I = c[p];
                V = (1.0f - s) * Vn;
                out[(size_t)(it + 1) * BO + obase] = s;
                c[p] = cn;
            }
        }
        // tail: it = 120..126 (c[7] holds cur[127] garbage, never consumed)
        #pragma unroll
        for (int p = 0; p < 7; ++p) {
            const int it = 120 + p;
            const float Vn = 0.9f * V + 0.1f * I;
            const float s = (Vn > 1.0f) ? 1.0f : 0.0f;
            I = c[p];
            V = (1.0f - s) * Vn;
            out[(size_t)(it + 1) * BO + obase] = s;
        }
    }
}

// ---------------------------------------------------------------------------
// Fallback GEMM (inline f32->bf16, 128x128, BK=32, f32 cur to out) if ws small.
// ---------------------------------------------------------------------------
__global__ __launch_bounds__(256, 2) void eventprop_gemm_f32in_kernel(
    const float* __restrict__ X, const float* __restrict__ W, float* __restrict__ C,
    const int K, const int N, const int nbn)
{
    __shared__ unsigned short As[128][32];
    __shared__ unsigned short Bs[128][32];
    const int bid = blockIdx.x;
    const int bm = bid / nbn, bn = bid % nbn;
    const int m0 = bm * 128, n0 = bn * 128;
    const int tid = threadIdx.x;
    const int lane = tid & 63;
    const int wave = tid >> 6;
    const int wr = wave >> 1, wc = wave & 1;
    const int lrow = lane & 15, kg = lane >> 4;

    f32x4 acc[4][4] = {};
    for (int kt = 0; kt < K; kt += 32) {
        #pragma unroll
        for (int p = 0; p < 4; ++p) {
            const int idx = p * 256 + tid;
            const int row = idx >> 3;
            const int c4  = (idx & 7) * 4;
            const float4 fa = *(const float4*)&X[(size_t)(m0 + row) * K + kt + c4];
            ushort4 ua; ua.x = f2bf(fa.x); ua.y = f2bf(fa.y); ua.z = f2bf(fa.z); ua.w = f2bf(fa.w);
            *(ushort4*)&As[row][c4] = ua;
            const float4 fb = *(const float4*)&W[(size_t)(n0 + row) * K + kt + c4];
            ushort4 ub; ub.x = f2bf(fb.x); ub.y = f2bf(fb.y); ub.z = f2bf(fb.z); ub.w = f2bf(fb.w);
            *(ushort4*)&Bs[row][c4] = ub;
        }
        __syncthreads();
        short8 a[4], b[4];
        #pragma unroll
        for (int mi = 0; mi < 4; ++mi) a[mi] = *(const short8*)&As[wr * 64 + mi * 16 + lrow][kg * 8];
        #pragma unroll
        for (int ni = 0; ni < 4; ++ni) b[ni] = *(const short8*)&Bs[wc * 64 + ni * 16 + lrow][kg * 8];
        #pragma unroll
        for (int mi = 0; mi < 4; ++mi)
            #pragma unroll
            for (int ni = 0; ni < 4; ++ni)
                acc[mi][ni] = __builtin_amdgcn_mfma_f32_16x16x32_bf16(a[mi], b[ni], acc[mi][ni], 0, 0, 0);
        __syncthreads();
    }
    const int r0 = kg * 4;
    #pragma unroll
    for (int mi = 0; mi < 4; ++mi)
        #pragma unroll
        for (int ni = 0; ni < 4; ++ni)
            #pragma unroll
            for (int r = 0; r < 4; ++r)
                C[(size_t)(m0 + wr * 64 + mi * 16 + r0 + r) * N + (n0 + wc * 64 + ni * 16 + lrow)] = acc[mi][ni][r];
}

// ---------------------------------------------------------------------------
// Fallback scan: in-place on d_out (f32 cur), 8-deep prefetch ring.
// ---------------------------------------------------------------------------
__global__ void eventprop_scan_kernel(float* __restrict__ out, const int BO)
{
    const int idx = blockIdx.x * blockDim.x + threadIdx.x;
    float V = 0.f, I = 0.f;
    float c[8];
    #pragma unroll
    for (int p = 0; p < 8; ++p)
        c[p] = out[(size_t)p * BO + idx];
    out[idx] = 0.f;
    #pragma unroll 1
    for (int i = 0; i < 120; i += 8) {
        #pragma unroll
        for (int p = 0; p < 8; ++p) {
            const int it = i + p;
            const float cn = out[(size_t)(it + 8) * BO + idx];
            const float Vn = 0.9f * V + 0.1f * I;
            const float s = (Vn > 1.0f) ? 1.0f : 0.0f;
            I = c[p];
            V = (1.0f - s) * Vn;
            out[(size_t)(it + 1) * BO + idx] = s;
            c[p] = cn;
        }
    }
    #pragma unroll
    for (int p = 0; p < 7; ++p) {
        const int it = 120 + p;
        const float Vn = 0.9f * V + 0.1f * I;
        const float s = (Vn > 1.0f) ? 1.0f : 0.0f;
        I = c[p];
        V = (1.0f - s) * Vn;
        out[(size_t)(it + 1) * BO + idx] = s;
    }
}

extern "C" void kernel_launch(void* const* d_in, const int* in_sizes, int n_in,
                              void* d_out, int out_size, void* d_ws, size_t ws_size,
                              hipStream_t stream) {
    const float* x = (const float*)d_in[0];   // [T, B, IN] f32
    const float* w = (const float*)d_in[1];   // [OUT, IN] f32
    float* out = (float*)d_out;               // [T, B, OUT] f32

    const int T = 128, B = 64, IN = 1024, OUT = 1024;
    const int Mpad = T * B;                   // 8192
    const int BO = B * OUT;                   // 65536
    const size_t nx = (size_t)Mpad * IN;      // 8388608
    const size_t nw = (size_t)OUT * IN;       // 1048576
    const size_t need = nx + nw;              // 9.4 MB (fp8)

    if (ws_size >= need) {
        unsigned char* x8 = (unsigned char*)d_ws;
        unsigned char* w8 = x8 + nx;
        const int ntot = (int)(nx + nw);
        const int cvt_blocks = (ntot / 8 + 255) / 256;  // 4608
        eventprop_cvt8_kernel<<<dim3(cvt_blocks), dim3(256), 0, stream>>>(x, w, x8, w8, (int)nx, ntot);
        const int nbn = OUT / 64;                        // 16
        const int nblocks = B * nbn;                     // 64 * 16 = 1024
        eventprop_gemm_scan_fp8_kernel<<<dim3(nblocks), dim3(256), 0, stream>>>(x8, w8, out, IN, OUT, nbn);
    } else {
        const int nbn = OUT / 128;
        const int nblocks = (Mpad / 128) * nbn;          // 512
        eventprop_gemm_f32in_kernel<<<dim3(nblocks), dim3(256), 0, stream>>>(x, w, out, IN, OUT, nbn);
        eventprop_scan_kernel<<<dim3(BO / 256), dim3(256), 0, stream>>>(out, BO);
    }
}